// Round 5
// baseline (206.399 us; speedup 1.0000x reference)
//
#include <hip/hip_runtime.h>
#include <hip/hip_bf16.h>

#define BB 8
#define SS 4096
#define DD 1024
#define NN 64
#define ROWS (BB * SS)          // 32768
#define GLD 256                 // 4 gates * 64
#define NCHUNK 256              // chunks per sequence
#define CLEN 16                 // steps per chunk (NCHUNK*CLEN == SS)

using bf16x8 = __attribute__((ext_vector_type(8))) short;
using f32x4  = __attribute__((ext_vector_type(4))) float;
typedef unsigned short ushort_t;

__device__ __forceinline__ ushort_t f2b(float f) {
    union { float f; unsigned int u; } v; v.f = f;
    unsigned int u = v.u;
    return (ushort_t)((u + 0x7fffu + ((u >> 16) & 1u)) >> 16);
}
__device__ __forceinline__ float b2f(ushort_t h) {
    union { unsigned int u; float f; } v; v.u = ((unsigned int)h) << 16;
    return v.f;
}

// ---------------- prep ----------------
// packed W' = ln_w ⊙ W, fragment-linear bf16 hi/lo: pW[s][cb][lane][8],
//   element = W'[cb*16 + (l&15)][s*32 + (l>>4)*8 + e]
// ball[c] = bias_c + sum_k ln_b[k]*W[c,k];  e_all[c] = sum_k ln_w[k]*W[c,k]
__global__ void prep_kernel(const float* __restrict__ Wi, const float* __restrict__ bi,
                            const float* __restrict__ Wf, const float* __restrict__ bfv,
                            const float* __restrict__ Wz, const float* __restrict__ bz,
                            const float* __restrict__ Wo, const float* __restrict__ bo,
                            const float* __restrict__ Wp,
                            const float* __restrict__ ln_w, const float* __restrict__ ln_b,
                            ushort_t* __restrict__ Wph, ushort_t* __restrict__ Wpl,
                            ushort_t* __restrict__ Wpb,
                            float* __restrict__ ball, float* __restrict__ e_all) {
    int i = blockIdx.x * 256 + threadIdx.x;
    if (i < 32768) {
        int l = i & 63, cb = (i >> 6) & 15, s = i >> 10;
        int r = cb * 16 + (l & 15);
        int c = s * 32 + (l >> 4) * 8;
        int g = r >> 6, rem = r & 63;
        const float* W = (g == 0) ? Wi : (g == 1) ? Wf : (g == 2) ? Wz : Wo;
        const float* src = W + rem * 1024 + c;
        const float* lwp = ln_w + c;
        bf16x8 hi8, lo8;
        #pragma unroll
        for (int e = 0; e < 8; ++e) {
            float w = src[e] * lwp[e];
            ushort_t hb = f2b(w);
            hi8[e] = (short)hb;
            lo8[e] = (short)f2b(w - b2f(hb));
        }
        *reinterpret_cast<bf16x8*>(Wph + (size_t)i * 8) = hi8;
        *reinterpret_cast<bf16x8*>(Wpl + (size_t)i * 8) = lo8;
    } else if (i < 32768 + 65536) {
        int j = i - 32768;
        Wpb[j] = f2b(Wp[j]);
    } else if (i < 32768 + 65536 + 256) {
        int j = i - (32768 + 65536);
        int g = j >> 6, rem = j & 63;
        const float* W = (g == 0) ? Wi : (g == 1) ? Wf : (g == 2) ? Wz : Wo;
        const float* bs = (g == 0) ? bi : (g == 1) ? bfv : (g == 2) ? bz : bo;
        const float* row = W + rem * 1024;
        float d = 0.0f, e = 0.0f;
        for (int k = 0; k < 1024; ++k) {
            float w = row[k];
            e += ln_w[k] * w;
            d += ln_b[k] * w;
        }
        ball[j] = bs[rem] + d;
        e_all[j] = e;
    }
}

// ---------------- fused LN-stats + gate GEMM (LN folded into W) ----------------
// block: 256 thr = 4 waves (1M x 4N). Tile 64 rows x 256 cols. Wave 64x64. Grid 512 (2/CU).
__global__ __launch_bounds__(256) void gate_gemm(const float* __restrict__ x,
                                                 const ushort_t* __restrict__ Wph,
                                                 const ushort_t* __restrict__ Wpl,
                                                 const float* __restrict__ ball,
                                                 const float* __restrict__ e_all,
                                                 float* __restrict__ gates) {
    int bm = blockIdx.x * 64;
    int tid = threadIdx.x;
    int wn = tid >> 6, lane = tid & 63;      // wn == gate index
    int lrow = lane & 15, lkg = lane >> 4;
    int srow = tid >> 2, skg = tid & 3;      // staging: row (0..63), 8-col k-group

    const float4* xrow = reinterpret_cast<const float4*>(x + (size_t)(bm + srow) * DD);

    // ---- stats prologue: whole-row sums (reads block's x tile from HBM once) ----
    float s1 = 0.0f, s2 = 0.0f;
    for (int j = 0; j < 32; ++j) {
        float4 v0 = xrow[j * 8 + skg * 2];
        float4 v1 = xrow[j * 8 + skg * 2 + 1];
        s1 += v0.x + v0.y + v0.z + v0.w + v1.x + v1.y + v1.z + v1.w;
        s2 += v0.x * v0.x + v0.y * v0.y + v0.z * v0.z + v0.w * v0.w
            + v1.x * v1.x + v1.y * v1.y + v1.z * v1.z + v1.w * v1.w;
    }
    s1 += __shfl_xor(s1, 1); s2 += __shfl_xor(s2, 1);
    s1 += __shfl_xor(s1, 2); s2 += __shfl_xor(s2, 2);

    __shared__ float2 stats_lds[64];
    if (skg == 0) {
        float mu = s1 * (1.0f / DD);
        float var = s2 * (1.0f / DD) - mu * mu;
        float rsd = rsqrtf(var + 1e-5f);
        float2 st; st.x = mu * rsd; st.y = rsd;   // (murs, rs)
        stats_lds[srow] = st;
    }

    // LDS: swizzled raw-x bf16 hi/lo planes, [buf][ (row*32+kg*8) ^ ((row&7)<<3) ]
    __shared__ ushort_t lds_h[2][2048];
    __shared__ ushort_t lds_l[2][2048];

    auto splitWrite = [&](float4 v0, float4 v1, int buf) {
        float xv[8] = {v0.x, v0.y, v0.z, v0.w, v1.x, v1.y, v1.z, v1.w};
        bf16x8 hi8, lo8;
        #pragma unroll
        for (int e = 0; e < 8; ++e) {
            ushort_t hb = f2b(xv[e]);
            hi8[e] = (short)hb;
            lo8[e] = (short)f2b(xv[e] - b2f(hb));
        }
        int idx = (srow * 32 + skg * 8) ^ ((srow & 7) << 3);
        *reinterpret_cast<bf16x8*>(&lds_h[buf][idx]) = hi8;
        *reinterpret_cast<bf16x8*>(&lds_l[buf][idx]) = lo8;
    };
    auto loadW = [&](bf16x8 (&w)[4][2], int s) {
        #pragma unroll
        for (int nf = 0; nf < 4; ++nf) {
            size_t base = (((size_t)(s * 16 + wn * 4 + nf)) * 64 + lane) * 8;
            w[nf][0] = *reinterpret_cast<const bf16x8*>(Wph + base);
            w[nf][1] = *reinterpret_cast<const bf16x8*>(Wpl + base);
        }
    };
    f32x4 acc[4][4] = {};
    auto compute = [&](int buf, bf16x8 (&w)[4][2]) {
        bf16x8 ah[4], al[4];
        #pragma unroll
        for (int mf = 0; mf < 4; ++mf) {
            int row = mf * 16 + lrow;
            int idx = (row * 32 + lkg * 8) ^ ((row & 7) << 3);
            ah[mf] = *reinterpret_cast<const bf16x8*>(&lds_h[buf][idx]);
            al[mf] = *reinterpret_cast<const bf16x8*>(&lds_l[buf][idx]);
        }
        #pragma unroll
        for (int nf = 0; nf < 4; ++nf) {
            #pragma unroll
            for (int mf = 0; mf < 4; ++mf) {
                acc[mf][nf] = __builtin_amdgcn_mfma_f32_16x16x32_bf16(ah[mf], w[nf][0], acc[mf][nf], 0, 0, 0);
                acc[mf][nf] = __builtin_amdgcn_mfma_f32_16x16x32_bf16(ah[mf], w[nf][1], acc[mf][nf], 0, 0, 0);
                acc[mf][nf] = __builtin_amdgcn_mfma_f32_16x16x32_bf16(al[mf], w[nf][0], acc[mf][nf], 0, 0, 0);
            }
        }
    };

    bf16x8 wA[4][2], wB[4][2];
    float4 xv0, xv1;
    // prologue: slice 0 staged, W(0) in flight
    xv0 = xrow[skg * 2]; xv1 = xrow[skg * 2 + 1];
    splitWrite(xv0, xv1, 0);
    loadW(wA, 0);
    __syncthreads();

    for (int it = 0; it < 16; ++it) {
        int s = 2 * it;
        // even slice s (buf 0, wA); prefetch s+1
        xv0 = xrow[(s + 1) * 8 + skg * 2];
        xv1 = xrow[(s + 1) * 8 + skg * 2 + 1];
        loadW(wB, s + 1);
        compute(0, wA);
        splitWrite(xv0, xv1, 1);
        __syncthreads();
        // odd slice s+1 (buf 1, wB); prefetch s+2
        if (it < 15) {
            xv0 = xrow[(s + 2) * 8 + skg * 2];
            xv1 = xrow[(s + 2) * 8 + skg * 2 + 1];
            loadW(wA, s + 2);
        }
        compute(1, wB);
        if (it < 15) splitWrite(xv0, xv1, 0);
        __syncthreads();
    }

    int c0 = wn * 64;
    int rb = (lane >> 4) * 4;
    #pragma unroll
    for (int mf = 0; mf < 4; ++mf) {
        #pragma unroll
        for (int nf = 0; nf < 4; ++nf) {
            int col = c0 + nf * 16 + (lane & 15);
            float bc = ball[col];
            float ec = e_all[col];
            #pragma unroll
            for (int r = 0; r < 4; ++r) {
                int rl = mf * 16 + rb + r;
                float2 st = stats_lds[rl];
                float v = acc[mf][nf][r] * st.y + bc - st.x * ec;
                float res;
                if (wn == 0 || wn == 1)      res = fminf(fmaxf(v, -20.0f), 20.0f);
                else if (wn == 2)            res = tanhf(v);
                else                         res = 1.0f / (1.0f + expf(-v));
                gates[(size_t)(bm + rl) * GLD + col] = res;
            }
        }
    }
}

// ---------------- scan phase A: per-chunk summaries ----------------
__global__ __launch_bounds__(256) void scan_a(const float* __restrict__ gates,
                                              float* __restrict__ sLf,
                                              float* __restrict__ sM,
                                              float* __restrict__ sC) {
    int w = blockIdx.x * 4 + (threadIdx.x >> 6);
    int lane = threadIdx.x & 63;
    int b = w >> 8, k = w & (NCHUNK - 1);
    int t0 = k * CLEN;
    const float* gp = gates + ((size_t)(b * SS + t0)) * GLD + lane;
    float Lf = 0.0f, m = -1e30f, c = 0.0f;
    for (int t = 0; t < CLEN; ++t) {
        float li = gp[0], lf = gp[64], z = gp[128];
        gp += GLD;
        Lf += lf;
        float ma = m + lf;
        float mn = fmaxf(ma, li);
        c = expf(ma - mn) * c + expf(li - mn) * z;
        m = mn;
    }
    int idx = (b * NCHUNK + k) * 64 + lane;
    sLf[idx] = Lf; sM[idx] = m; sC[idx] = c;
}

// ---------------- scan phase B: sequential compose over chunks (one block per batch) ----------------
__global__ __launch_bounds__(64) void scan_b(const float* __restrict__ sLf,
                                             const float* __restrict__ sM,
                                             const float* __restrict__ sC,
                                             float* __restrict__ cM,
                                             float* __restrict__ cC) {
    int b = blockIdx.x;
    int lane = threadIdx.x;
    float c = 0.0f, m = 0.0f;   // reference init: c0=0, m0=0
    for (int k = 0; k < NCHUNK; ++k) {
        int idx = (b * NCHUNK + k) * 64 + lane;
        cM[idx] = m; cC[idx] = c;
        float Lf = sLf[idx], ml = sM[idx], cl = sC[idx];
        float ma = m + Lf;
        float mo = fmaxf(ma, ml);
        c = expf(ma - mo) * c + expf(ml - mo) * cl;
        m = mo;
    }
}

// ---------------- scan phase C: replay chunks, emit h (bf16) ----------------
__global__ __launch_bounds__(256) void scan_c(const float* __restrict__ gates,
                                              const float* __restrict__ cM,
                                              const float* __restrict__ cC,
                                              ushort_t* __restrict__ h) {
    int w = blockIdx.x * 4 + (threadIdx.x >> 6);
    int lane = threadIdx.x & 63;
    int b = w >> 8, k = w & (NCHUNK - 1);
    int t0 = k * CLEN;
    int idx = (b * NCHUNK + k) * 64 + lane;
    float m = cM[idx], c = cC[idx];
    const float* gp = gates + ((size_t)(b * SS + t0)) * GLD + lane;
    ushort_t* hp = h + ((size_t)(b * SS + t0)) * NN + lane;
    for (int t = 0; t < CLEN; ++t) {
        float li = gp[0], lf = gp[64], z = gp[128], o = gp[192];
        gp += GLD;
        float ma = m + lf;
        float mn = fmaxf(ma, li);
        c = expf(ma - mn) * c + expf(li - mn) * z;
        m = mn;
        *hp = f2b(o * tanhf(c));
        hp += NN;
    }
}

// ---------------- output projection: h(32768x64) * Wpb^T(1024x64) + bp -> out ----------------
__global__ __launch_bounds__(256) void out_gemm(const ushort_t* __restrict__ h,
                                                const ushort_t* __restrict__ Wpb,
                                                const float* __restrict__ bp,
                                                float* __restrict__ out) {
    int tid = threadIdx.x, wid = tid >> 6, lane = tid & 63;
    int r0 = (blockIdx.x >> 1) * 32;
    int c0 = (blockIdx.x & 1) * 512 + wid * 128;
    int lrow = lane & 15, lk = (lane >> 4) * 8;

    f32x4 acc[2][8] = {};
    #pragma unroll
    for (int ks = 0; ks < 2; ++ks) {
        int kk = ks * 32;
        bf16x8 a[2], bfr[8];
        #pragma unroll
        for (int mf = 0; mf < 2; ++mf)
            a[mf] = *reinterpret_cast<const bf16x8*>(h + (size_t)(r0 + mf * 16 + lrow) * NN + kk + lk);
        #pragma unroll
        for (int nf = 0; nf < 8; ++nf)
            bfr[nf] = *reinterpret_cast<const bf16x8*>(Wpb + (size_t)(c0 + nf * 16 + lrow) * NN + kk + lk);
        #pragma unroll
        for (int mf = 0; mf < 2; ++mf)
            #pragma unroll
            for (int nf = 0; nf < 8; ++nf)
                acc[mf][nf] = __builtin_amdgcn_mfma_f32_16x16x32_bf16(a[mf], bfr[nf], acc[mf][nf], 0, 0, 0);
    }
    int rb = (lane >> 4) * 4;
    #pragma unroll
    for (int nf = 0; nf < 8; ++nf) {
        int col = c0 + nf * 16 + (lane & 15);
        float bias = bp[col];
        #pragma unroll
        for (int mf = 0; mf < 2; ++mf) {
            #pragma unroll
            for (int r = 0; r < 4; ++r) {
                int row = r0 + mf * 16 + rb + r;
                out[(size_t)row * DD + col] = acc[mf][nf][r] + bias;
            }
        }
    }
}

extern "C" void kernel_launch(void* const* d_in, const int* in_sizes, int n_in,
                              void* d_out, int out_size, void* d_ws, size_t ws_size,
                              hipStream_t stream) {
    const float* x    = (const float*)d_in[0];
    const float* ln_w = (const float*)d_in[1];
    const float* ln_b = (const float*)d_in[2];
    const float* Wi   = (const float*)d_in[3];
    const float* bi   = (const float*)d_in[4];
    const float* Wf   = (const float*)d_in[5];
    const float* bfv  = (const float*)d_in[6];
    const float* Wz   = (const float*)d_in[7];
    const float* bz   = (const float*)d_in[8];
    const float* Wo   = (const float*)d_in[9];
    const float* bo   = (const float*)d_in[10];
    const float* Wp   = (const float*)d_in[11];
    const float* bp   = (const float*)d_in[12];
    float* out = (float*)d_out;

    // gates fp32 [32768][256] at d_out floats [0, 8.39M)  (33.5 MB; dead before out_gemm)
    float* gates = (float*)d_out;
    // chunk summaries in dead d_out space (floats from 9M; 5 x 131072 floats)
    float* sbase = (float*)d_out + 9 * 1024 * 1024;
    float* sLf = sbase;
    float* sM  = sbase + 1 * (BB * NCHUNK * 64);
    float* sC  = sbase + 2 * (BB * NCHUNK * 64);
    float* cM  = sbase + 3 * (BB * NCHUNK * 64);
    float* cC  = sbase + 4 * (BB * NCHUNK * 64);

    // Small scratch in ws (~5.3 MB)
    char* w = (char*)d_ws;
    ushort_t* h   = (ushort_t*)w; w += (size_t)ROWS * NN * 2;       // 4,194,304
    ushort_t* Wph = (ushort_t*)w; w += 256 * 1024 * 2;              // 524,288
    ushort_t* Wpl = (ushort_t*)w; w += 256 * 1024 * 2;              // 524,288
    ushort_t* Wpb = (ushort_t*)w; w += 1024 * 64 * 2;               // 131,072
    float* ball   = (float*)w;    w += 256 * 4;                     // 1,024
    float* e_all  = (float*)w;    w += 256 * 4;                     // 1,024

    prep_kernel<<<386, 256, 0, stream>>>(Wi, bi, Wf, bfv, Wz, bz, Wo, bo, Wp,
                                         ln_w, ln_b, Wph, Wpl, Wpb, ball, e_all);
    gate_gemm<<<ROWS / 64, 256, 0, stream>>>(x, Wph, Wpl, ball, e_all, gates);
    scan_a<<<(BB * NCHUNK) / 4, 256, 0, stream>>>(gates, sLf, sM, sC);
    scan_b<<<BB, 64, 0, stream>>>(sLf, sM, sC, cM, cC);
    scan_c<<<(BB * NCHUNK) / 4, 256, 0, stream>>>(gates, cM, cC, h);
    out_gemm<<<(ROWS / 32) * 2, 256, 0, stream>>>(h, Wpb, bp, out);
}